// Round 4
// baseline (1178.993 us; speedup 1.0000x reference)
//
#include <hip/hip_runtime.h>

#define SEQ   4096
#define HID   4096
#define EDIM  1024
#define NHEAD 4

typedef __attribute__((ext_vector_type(8))) short short8;
typedef __attribute__((ext_vector_type(4))) float f32x4;

typedef const __attribute__((address_space(1))) void* gas_ptr;
typedef __attribute__((address_space(3))) void* las_ptr;
#define GLD16(g, l) __builtin_amdgcn_global_load_lds((gas_ptr)(g), (las_ptr)(l), 16, 0, 0)

#define BARRIER() __builtin_amdgcn_s_barrier()
#define SCHED0()  __builtin_amdgcn_sched_barrier(0)

__device__ __forceinline__ unsigned short f2bf(float f) {
  union { float f; unsigned u; } v; v.f = f;
  unsigned r = v.u + 0x7fffu + ((v.u >> 16) & 1u);  // RNE
  return (unsigned short)(r >> 16);
}
__device__ __forceinline__ float bf2f(unsigned short u) {
  union { unsigned u; float f; } v; v.u = ((unsigned)u) << 16;
  return v.f;
}

// ---------------- h: f32 -> bf16 ----------------
__global__ __launch_bounds__(256) void hconv_kernel(const float* __restrict__ in,
                                                    unsigned short* __restrict__ out) {
  size_t i = ((size_t)blockIdx.x * 256 + threadIdx.x) * 8;
  const float4 a = *(const float4*)(in + i);
  const float4 b = *(const float4*)(in + i + 4);
  short8 o;
  o[0] = (short)f2bf(a.x); o[1] = (short)f2bf(a.y);
  o[2] = (short)f2bf(a.z); o[3] = (short)f2bf(a.w);
  o[4] = (short)f2bf(b.x); o[5] = (short)f2bf(b.y);
  o[6] = (short)f2bf(b.z); o[7] = (short)f2bf(b.w);
  *(short8*)(out + i) = o;
}

// ---------------- W [mat][head][D][E] f32 -> Wt [mat*4+head][E][D] bf16 ----------------
__global__ __launch_bounds__(256) void wconv_kernel(const float* __restrict__ Wq,
                                                    const float* __restrict__ Wk,
                                                    const float* __restrict__ Wv,
                                                    unsigned short* __restrict__ wt) {
  const int mh = blockIdx.y;               // 0..11
  const int mat = mh >> 2, head = mh & 3;
  const float* W = (mat == 0 ? Wq : (mat == 1 ? Wk : Wv)) + (size_t)head * HID * EDIM; // [D][E]
  unsigned short* out = wt + (size_t)mh * EDIM * HID;                                  // [E][D]
  const int tile = blockIdx.x;             // (D/64)*(E/64) = 64*16
  const int td = tile >> 4;                // d-tile 0..63
  const int te = tile & 15;                // e-tile 0..15
  __shared__ float lds[64][65];
  const int tid = threadIdx.x;
  const int r = tid >> 4, c4 = (tid & 15) * 4;
#pragma unroll
  for (int it = 0; it < 4; ++it) {
    int dr = r + 16 * it;
    const float4 v = *(const float4*)&W[(size_t)(td * 64 + dr) * EDIM + te * 64 + c4];
    lds[dr][c4 + 0] = v.x; lds[dr][c4 + 1] = v.y;
    lds[dr][c4 + 2] = v.z; lds[dr][c4 + 3] = v.w;
  }
  __syncthreads();
#pragma unroll
  for (int it = 0; it < 4; ++it) {
    int er = r + 16 * it;
    ushort4 o;
    o.x = f2bf(lds[c4 + 0][er]); o.y = f2bf(lds[c4 + 1][er]);
    o.z = f2bf(lds[c4 + 2][er]); o.w = f2bf(lds[c4 + 3][er]);
    *(ushort4*)&out[(size_t)(te * 64 + er) * HID + td * 64 + c4] = o;
  }
}

// ---------------- 256x256 pipelined 8-phase bf16 MFMA GEMM, C = A * Bt^T ----------------
// BK=64, 8 waves (2Mx4N, 128x64/wave), 2-slot LDS double buffer. One-phase-ahead
// fragment pipeline: phase p issues ds_reads for phase p+1, waits counted
// lgkmcnt(=reads just issued) which drains the PREVIOUS phase's reads, then MFMAs.
// Per-tile: q1 || read bvH (4), q2 || read avH (8), q3 || 0, q4 || read next tile's
// avL+bvL (12) after vmcnt(4)+barrier proved next slot landed (q4 needs no lgkm wait).
// Staging: ph1:A0(t+1) ph2:A1(t+1) ph3:B0(t+2) ph4:B1(t+2) (same for odd tile, +1).
// vmcnt(4) at q4 = drains exactly tiles through t+1 (queue math verified r3).
// XOR swizzle: phys 16B-slot = logical k-slot ^ (row&7); staging source pre-permuted.
// MODE 0: bf16 out [row][col], +bias[col]
// MODE 1: bf16 out [col][row], +bias[col]   (transposed write, for V^T)
// MODE 2: bf16 out [row][col], *scale       (scores)
// MODE 3: f32  out [row][col]               (final output)
template <int MODE>
__global__ __launch_bounds__(512, 2) void gemm256_kernel(
    const unsigned short* __restrict__ Aall, const unsigned short* __restrict__ Ball,
    long long aBatch, long long bBatch, int K,
    const float* __restrict__ biasAll, long long biasBatch,
    void* __restrict__ outAll, long long outBatch, int ldOut, float scale,
    int gx, int gxy) {
  extern __shared__ char smem[];

  // XCD-aware bijective block swizzle (all grids have nwg % 8 == 0)
  const int nwg = (int)gridDim.x;
  const int lin = (int)blockIdx.x;
  int wg = (lin & 7) * (nwg >> 3) + (lin >> 3);
  const int z = wg / gxy; wg -= z * gxy;
  const int by = wg / gx;
  const int bx = wg - by * gx;
  const int bm = by * 256, bn = bx * 256;

  const unsigned short* A = Aall + (size_t)z * aBatch;
  const unsigned short* B = Ball + (size_t)z * bBatch;

  const int tid = threadIdx.x;           // 0..511
  const int lane = tid & 63, wid = tid >> 6;
  const int wr = wid >> 2, wc = wid & 3; // wave -> (2 x 4) output grid
  const int li = lane & 15, lg = lane >> 4;

  // ---- staging addresses: half-tile = 128 rows x 64 k = 1024 16B chunks.
  const int srow = tid >> 3;                               // 0..63
  const int sk = ((tid & 7) ^ (srow & 7)) * 8;             // pre-permuted k-slot
  const unsigned short* aS00 = A + (size_t)(bm +   0 + srow) * K + sk;
  const unsigned short* aS01 = A + (size_t)(bm +  64 + srow) * K + sk;
  const unsigned short* aS10 = A + (size_t)(bm + 128 + srow) * K + sk;
  const unsigned short* aS11 = A + (size_t)(bm + 192 + srow) * K + sk;
  const unsigned short* bS00 = B + (size_t)(bn +   0 + srow) * K + sk;
  const unsigned short* bS01 = B + (size_t)(bn +  64 + srow) * K + sk;
  const unsigned short* bS10 = B + (size_t)(bn + 128 + srow) * K + sk;
  const unsigned short* bS11 = B + (size_t)(bn + 192 + srow) * K + sk;

// regionOff: A half0=0, A half1=16384, B half0=32768, B half1=49152
#define STG(p0, p1, regionOff, tt)                                        \
  do {                                                                    \
    char* _d = smem + (((tt) & 1) << 16) + (regionOff) + tid * 16;        \
    GLD16((p0) + (size_t)(tt) * 64, _d);                                  \
    GLD16((p1) + (size_t)(tt) * 64, _d + 8192);                           \
  } while (0)

  // ---- swizzled ds_read bases: row stride 128B, slot = (ks*4+lg) ^ (li&7)
  const int aBase = (wr * 128 + li) * 128;
  const int bBase = 32768 + (wc * 64 + li) * 128;
  const int axk0 = ((0 + lg) ^ (li & 7)) * 16;   // ks=0
  const int axk1 = ((4 + lg) ^ (li & 7)) * 16;   // ks=1

  f32x4 acc[8][4];
#pragma unroll
  for (int m = 0; m < 8; ++m)
#pragma unroll
    for (int n = 0; n < 4; ++n) acc[m][n] = (f32x4){0.f, 0.f, 0.f, 0.f};

  const int NT = K >> 6;    // K-tiles of 64
  const int NI = NT >> 1;

  short8 avL[4][2], avH[4][2], bvL[2][2], bvH[2][2];

#define RD_AVL(S)                                                          \
  _Pragma("unroll") for (int m = 0; m < 4; ++m) {                          \
    avL[m][0] = *(const short8*)((S) + aBase + m * 2048 + axk0);           \
    avL[m][1] = *(const short8*)((S) + aBase + m * 2048 + axk1);           \
  }
#define RD_AVH(S)                                                          \
  _Pragma("unroll") for (int m = 0; m < 4; ++m) {                          \
    avH[m][0] = *(const short8*)((S) + aBase + (m + 4) * 2048 + axk0);     \
    avH[m][1] = *(const short8*)((S) + aBase + (m + 4) * 2048 + axk1);     \
  }
#define RD_BVL(S)                                                          \
  _Pragma("unroll") for (int n = 0; n < 2; ++n) {                          \
    bvL[n][0] = *(const short8*)((S) + bBase + n * 2048 + axk0);           \
    bvL[n][1] = *(const short8*)((S) + bBase + n * 2048 + axk1);           \
  }
#define RD_BVH(S)                                                          \
  _Pragma("unroll") for (int n = 0; n < 2; ++n) {                          \
    bvH[n][0] = *(const short8*)((S) + bBase + (n + 2) * 2048 + axk0);     \
    bvH[n][1] = *(const short8*)((S) + bBase + (n + 2) * 2048 + axk1);     \
  }
#define MFMA_Q(AV, BV, MO, NO)                                             \
  _Pragma("unroll") for (int m = 0; m < 4; ++m)                            \
  _Pragma("unroll") for (int n = 0; n < 2; ++n) {                          \
    acc[m + MO][n + NO] = __builtin_amdgcn_mfma_f32_16x16x32_bf16(         \
        AV[m][0], BV[n][0], acc[m + MO][n + NO], 0, 0, 0);                 \
    acc[m + MO][n + NO] = __builtin_amdgcn_mfma_f32_16x16x32_bf16(         \
        AV[m][1], BV[n][1], acc[m + MO][n + NO], 0, 0, 0);                 \
  }
#define LGKM(N) asm volatile("s_waitcnt lgkmcnt(" #N ")" ::: "memory")
#define VMC(N)  asm volatile("s_waitcnt vmcnt(" #N ")" ::: "memory")

  // ---- prologue: stage A(0),B(0),B(1); wait tile0 landed; read tile0 avL,bvL
  STG(aS00, aS01, 0, 0);
  STG(aS10, aS11, 16384, 0);
  STG(bS00, bS01, 32768, 0);
  STG(bS10, bS11, 49152, 0);
  STG(bS00, bS01, 32768, 1);
  STG(bS10, bS11, 49152, 1);
  VMC(4);
  BARRIER();
  SCHED0();
  RD_AVL(smem); RD_BVL(smem);
  SCHED0();

  for (int i = 0; i < NI; ++i) {
    const int t = 2 * i;
    const char* s0 = smem;            // even tile slot
    const char* s1 = smem + 65536;    // odd tile slot

    // ===== q1(t): MFMA avL x bvL || read bvH(s0) =====
    RD_BVH(s0);
    SCHED0();
    STG(aS00, aS01, 0, t + 1);
    LGKM(4);                // prev-phase reads (avL,bvL) complete
    SCHED0();
    __builtin_amdgcn_s_setprio(1);
    MFMA_Q(avL, bvL, 0, 0);
    __builtin_amdgcn_s_setprio(0);
    SCHED0();
    BARRIER();
    SCHED0();

    // ===== q2(t): MFMA avL x bvH || read avH(s0) =====
    RD_AVH(s0);
    SCHED0();
    STG(aS10, aS11, 16384, t + 1);
    LGKM(8);                // bvH complete
    SCHED0();
    __builtin_amdgcn_s_setprio(1);
    MFMA_Q(avL, bvH, 0, 2);
    __builtin_amdgcn_s_setprio(0);
    SCHED0();
    BARRIER();
    SCHED0();

    // ===== q3(t): MFMA avH x bvL || no reads =====
    if (t + 2 < NT) STG(bS00, bS01, 32768, t + 2);
    LGKM(0);                // avH complete
    SCHED0();
    __builtin_amdgcn_s_setprio(1);
    MFMA_Q(avH, bvL, 4, 0);
    __builtin_amdgcn_s_setprio(0);
    SCHED0();
    BARRIER();
    SCHED0();

    // ===== q4(t): MFMA avH x bvH || read next tile avL,bvL (s1) =====
    if (t + 2 < NT) {
      STG(bS10, bS11, 49152, t + 2);
      VMC(4);               // tiles through t+1 landed
    } else {
      VMC(0);
    }
    SCHED0();
    BARRIER();
    SCHED0();
    RD_AVL(s1); RD_BVL(s1);
    SCHED0();
    __builtin_amdgcn_s_setprio(1);
    MFMA_Q(avH, bvH, 4, 2); // deps already drained (no lgkm wait)
    __builtin_amdgcn_s_setprio(0);
    SCHED0();
    BARRIER();
    SCHED0();

    // ===== q1(t+1): MFMA avL x bvL || read bvH(s1) =====
    RD_BVH(s1);
    SCHED0();
    if (t + 2 < NT) STG(aS00, aS01, 0, t + 2);
    LGKM(4);
    SCHED0();
    __builtin_amdgcn_s_setprio(1);
    MFMA_Q(avL, bvL, 0, 0);
    __builtin_amdgcn_s_setprio(0);
    SCHED0();
    BARRIER();
    SCHED0();

    // ===== q2(t+1): MFMA avL x bvH || read avH(s1) =====
    RD_AVH(s1);
    SCHED0();
    if (t + 2 < NT) STG(aS10, aS11, 16384, t + 2);
    LGKM(8);
    SCHED0();
    __builtin_amdgcn_s_setprio(1);
    MFMA_Q(avL, bvH, 0, 2);
    __builtin_amdgcn_s_setprio(0);
    SCHED0();
    BARRIER();
    SCHED0();

    // ===== q3(t+1): MFMA avH x bvL =====
    if (t + 3 < NT) STG(bS00, bS01, 32768, t + 3);
    LGKM(0);
    SCHED0();
    __builtin_amdgcn_s_setprio(1);
    MFMA_Q(avH, bvL, 4, 0);
    __builtin_amdgcn_s_setprio(0);
    SCHED0();
    BARRIER();
    SCHED0();

    // ===== q4(t+1): MFMA avH x bvH || read tile t+2 avL,bvL (s0) =====
    if (t + 3 < NT) {
      STG(bS10, bS11, 49152, t + 3);
      VMC(4);
    } else {
      VMC(0);
    }
    SCHED0();
    BARRIER();
    SCHED0();
    if (i + 1 < NI) {
      RD_AVL(s0); RD_BVL(s0);
    }
    SCHED0();
    __builtin_amdgcn_s_setprio(1);
    MFMA_Q(avH, bvH, 4, 2);
    __builtin_amdgcn_s_setprio(0);
    SCHED0();
    BARRIER();
    SCHED0();
  }
#undef STG
#undef RD_AVL
#undef RD_AVH
#undef RD_BVL
#undef RD_BVH
#undef MFMA_Q
#undef LGKM
#undef VMC

  // ---- epilogue
  float bvv[4];
  if (MODE == 0 || MODE == 1) {
    const float* bias = biasAll + (size_t)z * biasBatch;
#pragma unroll
    for (int n = 0; n < 4; ++n) bvv[n] = bias[bn + wc * 64 + n * 16 + li];
  }
#pragma unroll
  for (int m = 0; m < 8; ++m)
#pragma unroll
    for (int n = 0; n < 4; ++n)
#pragma unroll
      for (int r = 0; r < 4; ++r) {
        const int grow = bm + wr * 128 + m * 16 + lg * 4 + r;
        const int gcol = bn + wc * 64 + n * 16 + li;
        float val = acc[m][n][r];
        if (MODE == 0 || MODE == 1) val += bvv[n];
        if (MODE == 2) val *= scale;
        if (MODE == 0 || MODE == 2) {
          unsigned short* o = (unsigned short*)outAll + (size_t)z * outBatch;
          o[(size_t)grow * ldOut + gcol] = f2bf(val);
        } else if (MODE == 1) {
          unsigned short* o = (unsigned short*)outAll + (size_t)z * outBatch;
          o[(size_t)gcol * ldOut + grow] = f2bf(val);
        } else {
          float* o = (float*)outAll + (size_t)z * outBatch;
          o[(size_t)grow * ldOut + gcol] = val;
        }
      }
}

// ---------------- row softmax, in place on bf16 [nrows][SEQ] ----------------
__global__ __launch_bounds__(256) void softmax_kernel(unsigned short* __restrict__ Sb) {
  const size_t row = blockIdx.x;
  unsigned short* p = Sb + row * (size_t)SEQ;
  const int tid = threadIdx.x;
  const int lane = tid & 63, wid = tid >> 6;
  float v[16];
  const short8 u0 = *(const short8*)&p[tid * 16];
  const short8 u1 = *(const short8*)&p[tid * 16 + 8];
#pragma unroll
  for (int j = 0; j < 8; ++j) v[j] = bf2f((unsigned short)u0[j]);
#pragma unroll
  for (int j = 0; j < 8; ++j) v[8 + j] = bf2f((unsigned short)u1[j]);
  float mx = v[0];
#pragma unroll
  for (int j = 1; j < 16; ++j) mx = fmaxf(mx, v[j]);
#pragma unroll
  for (int off = 32; off; off >>= 1) mx = fmaxf(mx, __shfl_xor(mx, off));
  __shared__ float red[8];
  if (lane == 0) red[wid] = mx;
  __syncthreads();
  mx = fmaxf(fmaxf(red[0], red[1]), fmaxf(red[2], red[3]));
  float s = 0.f;
#pragma unroll
  for (int j = 0; j < 16; ++j) { v[j] = __expf(v[j] - mx); s += v[j]; }
#pragma unroll
  for (int off = 32; off; off >>= 1) s += __shfl_xor(s, off);
  if (lane == 0) red[4 + wid] = s;
  __syncthreads();
  s = (red[4] + red[5]) + (red[6] + red[7]);
  const float inv = 1.0f / s;
  short8 o0, o1;
#pragma unroll
  for (int j = 0; j < 8; ++j) o0[j] = (short)f2bf(v[j] * inv);
#pragma unroll
  for (int j = 0; j < 8; ++j) o1[j] = (short)f2bf(v[8 + j] * inv);
  *(short8*)&p[tid * 16] = o0;
  *(short8*)&p[tid * 16 + 8] = o1;
}

extern "C" void kernel_launch(void* const* d_in, const int* in_sizes, int n_in,
                              void* d_out, int out_size, void* d_ws, size_t ws_size,
                              hipStream_t stream) {
  const float* h  = (const float*)d_in[0];
  const float* Wq = (const float*)d_in[1];
  const float* bq = (const float*)d_in[2];
  const float* Wk = (const float*)d_in[3];
  const float* bk = (const float*)d_in[4];
  const float* Wv = (const float*)d_in[5];
  const float* bv = (const float*)d_in[6];
  float* out = (float*)d_out;
  char* ws = (char*)d_ws;

  // allow 128KB dynamic LDS for the GEMM kernels (idempotent, not a stream op)
  (void)hipFuncSetAttribute((const void*)&gemm256_kernel<0>,
                            hipFuncAttributeMaxDynamicSharedMemorySize, 131072);
  (void)hipFuncSetAttribute((const void*)&gemm256_kernel<1>,
                            hipFuncAttributeMaxDynamicSharedMemorySize, 131072);
  (void)hipFuncSetAttribute((const void*)&gemm256_kernel<2>,
                            hipFuncAttributeMaxDynamicSharedMemorySize, 131072);
  (void)hipFuncSetAttribute((const void*)&gemm256_kernel<3>,
                            hipFuncAttributeMaxDynamicSharedMemorySize, 131072);

  // ws layout (224 MB):
  //  [0,32MB)    h_bf16 [S][HID]          -- dead after projections
  //  [32,128MB)  Wt bf16 [12][E][HID]     -- dead after projections
  //  [0,128MB)   Sb bf16 [H][S][S]        -- scores/probs (reuses the two above)
  //  [128,160)   Qb bf16 [H][S][E]
  //  [160,192)   Kb bf16 [H][S][E]
  //  [192,224)   Vt bf16 [H][E][S]
  unsigned short* hB = (unsigned short*)ws;
  unsigned short* wt = (unsigned short*)(ws + (32ull << 20));
  unsigned short* Sb = (unsigned short*)ws;
  unsigned short* Qb = (unsigned short*)(ws + (128ull << 20));
  unsigned short* Kb = (unsigned short*)(ws + (160ull << 20));
  unsigned short* Vt = (unsigned short*)(ws + (192ull << 20));

  const long long WED = (long long)EDIM * HID;   // per-(mat,head) Wt elems
  const long long QKB = (long long)SEQ * EDIM;   // per-head Q/K elems
  const long long SSB = (long long)SEQ * SEQ;    // per-head score elems

  hconv_kernel<<<dim3((SEQ * (size_t)HID) / (256 * 8)), 256, 0, stream>>>(h, hB);
  wconv_kernel<<<dim3((HID / 64) * (EDIM / 64), 12), 256, 0, stream>>>(Wq, Wk, Wv, wt);

  // Projections: M=S=4096, N=E=1024, K=HID  -> grid (4 x 16 x 4) = 256 blocks, 1-D
  gemm256_kernel<0><<<dim3(4 * 16 * 4), 512, 131072, stream>>>(
      hB, wt + 0 * WED, 0, WED, HID, bq, EDIM, Qb, QKB, EDIM, 1.f, 4, 64);
  gemm256_kernel<0><<<dim3(4 * 16 * 4), 512, 131072, stream>>>(
      hB, wt + 4 * WED, 0, WED, HID, bk, EDIM, Kb, QKB, EDIM, 1.f, 4, 64);
  gemm256_kernel<1><<<dim3(4 * 16 * 4), 512, 131072, stream>>>(
      hB, wt + 8 * WED, 0, WED, HID, bv, EDIM, Vt, QKB, SEQ, 1.f, 4, 64);

  // Scores: S = Q K^T / 32   (M=N=S, K=E) -> grid (16 x 16 x 4) = 1024 blocks
  gemm256_kernel<2><<<dim3(16 * 16 * 4), 512, 131072, stream>>>(
      Qb, Kb, QKB, QKB, EDIM, nullptr, 0, Sb, SSB, SEQ, 0.03125f, 16, 256);

  // Softmax over rows, in place
  softmax_kernel<<<dim3(NHEAD * SEQ), 256, 0, stream>>>(Sb);

  // Out: O = P V  (M=S, N=E, K=S), written to out[s][head*E + e] as f32
  gemm256_kernel<3><<<dim3(4 * 16 * 4), 512, 131072, stream>>>(
      Sb, Vt, SSB, QKB, SEQ, nullptr, 0, out, (long long)EDIM, NHEAD * EDIM, 1.f, 4, 64);
}

// Round 5
// 783.072 us; speedup vs baseline: 1.5056x; 1.5056x over previous
//
#include <hip/hip_runtime.h>

#define SEQ   4096
#define HID   4096
#define EDIM  1024
#define NHEAD 4

typedef __attribute__((ext_vector_type(8))) short short8;
typedef __attribute__((ext_vector_type(16))) float f32x16;

typedef const __attribute__((address_space(1))) void* gas_ptr;
typedef __attribute__((address_space(3))) void* las_ptr;
#define GLD16(g, l) __builtin_amdgcn_global_load_lds((gas_ptr)(g), (las_ptr)(l), 16, 0, 0)

#define BARRIER() __builtin_amdgcn_s_barrier()
#define SCHED0()  __builtin_amdgcn_sched_barrier(0)
#define LGKM0()   asm volatile("s_waitcnt lgkmcnt(0)" ::: "memory")
#define VMC(N)    asm volatile("s_waitcnt vmcnt(" #N ")" ::: "memory")

__device__ __forceinline__ unsigned short f2bf(float f) {
  union { float f; unsigned u; } v; v.f = f;
  unsigned r = v.u + 0x7fffu + ((v.u >> 16) & 1u);  // RNE
  return (unsigned short)(r >> 16);
}
__device__ __forceinline__ float bf2f(unsigned short u) {
  union { unsigned u; float f; } v; v.u = ((unsigned)u) << 16;
  return v.f;
}

// ---------------- h: f32 -> bf16 ----------------
__global__ __launch_bounds__(256) void hconv_kernel(const float* __restrict__ in,
                                                    unsigned short* __restrict__ out) {
  size_t i = ((size_t)blockIdx.x * 256 + threadIdx.x) * 8;
  const float4 a = *(const float4*)(in + i);
  const float4 b = *(const float4*)(in + i + 4);
  short8 o;
  o[0] = (short)f2bf(a.x); o[1] = (short)f2bf(a.y);
  o[2] = (short)f2bf(a.z); o[3] = (short)f2bf(a.w);
  o[4] = (short)f2bf(b.x); o[5] = (short)f2bf(b.y);
  o[6] = (short)f2bf(b.z); o[7] = (short)f2bf(b.w);
  *(short8*)(out + i) = o;
}

// ---------------- W [mat][head][D][E] f32 -> Wt [mat*4+head][E][D] bf16 ----------------
__global__ __launch_bounds__(256) void wconv_kernel(const float* __restrict__ Wq,
                                                    const float* __restrict__ Wk,
                                                    const float* __restrict__ Wv,
                                                    unsigned short* __restrict__ wt) {
  const int mh = blockIdx.y;               // 0..11
  const int mat = mh >> 2, head = mh & 3;
  const float* W = (mat == 0 ? Wq : (mat == 1 ? Wk : Wv)) + (size_t)head * HID * EDIM; // [D][E]
  unsigned short* out = wt + (size_t)mh * EDIM * HID;                                  // [E][D]
  const int tile = blockIdx.x;             // (D/64)*(E/64) = 64*16
  const int td = tile >> 4;                // d-tile 0..63
  const int te = tile & 15;                // e-tile 0..15
  __shared__ float lds[64][65];
  const int tid = threadIdx.x;
  const int r = tid >> 4, c4 = (tid & 15) * 4;
#pragma unroll
  for (int it = 0; it < 4; ++it) {
    int dr = r + 16 * it;
    const float4 v = *(const float4*)&W[(size_t)(td * 64 + dr) * EDIM + te * 64 + c4];
    lds[dr][c4 + 0] = v.x; lds[dr][c4 + 1] = v.y;
    lds[dr][c4 + 2] = v.z; lds[dr][c4 + 3] = v.w;
  }
  __syncthreads();
#pragma unroll
  for (int it = 0; it < 4; ++it) {
    int er = r + 16 * it;
    ushort4 o;
    o.x = f2bf(lds[c4 + 0][er]); o.y = f2bf(lds[c4 + 1][er]);
    o.z = f2bf(lds[c4 + 2][er]); o.w = f2bf(lds[c4 + 3][er]);
    *(ushort4*)&out[(size_t)(te * 64 + er) * HID + td * 64 + c4] = o;
  }
}

// ---------------- 256x256 bf16 MFMA GEMM (32x32x16), C = A * Bt^T ----------------
// BK=64, 8 waves (2Mx4N, 128x64/wave), wave tile = 4x2 tiles of 32x32 (acc f32x16[4][2]).
// 2-slot LDS double buffer (64KB/tile), 2 phases/tile:
//   ph1: read A[m0-1][ks0-3] (8 b128) + B[n0-1][ks0-3] (8) || STG A(t+1) -> other slot;
//        BAR; lgkm(0); 16 MFMA (m0-1);
//   ph2: read A[m2-3] (8, reusing av regs via in-order WAR) || STG B(t+2) -> same slot
//        (B(t) fully read in ph1 -> region dead); BAR; lgkm(0); 16 MFMA (m2-3);
//        vmcnt(4) (drains A(t+1),B(t+1); B(t+2)'s 4 insts stay in flight); BAR.
// Swizzle: phys 16B-slot = logical k-chunk ^ f(row), f(row)=(row^(row>>3))&7 -- conflict-
// free per 8-lane group for 32-row fragment spans; staging source pre-permuted with the
// same involution (f(row+64)=f(row), so one sk serves both GLD halves).
// Frag maps: A/B lane l: row/col = l&31, k = (l>>5)*8 + j (analog of verified 16x16x32).
// C/D (verified m74/m101): col = lane&31, row = (reg&3) + 8*(reg>>2) + 4*(lane>>5).
// MODE 0: bf16 out [row][col], +bias[col]
// MODE 1: bf16 out [col][row], +bias[col]   (transposed write, for V^T)
// MODE 2: bf16 out [row][col], *scale       (scores)
// MODE 3: f32  out [row][col]               (final output)
template <int MODE>
__global__ __launch_bounds__(512, 2) void gemm256_kernel(
    const unsigned short* __restrict__ Aall, const unsigned short* __restrict__ Ball,
    long long aBatch, long long bBatch, int K,
    const float* __restrict__ biasAll, long long biasBatch,
    void* __restrict__ outAll, long long outBatch, int ldOut, float scale,
    int gx, int gxy) {
  extern __shared__ char smem[];

  // XCD-aware bijective block swizzle (all grids have nwg % 8 == 0)
  const int nwg = (int)gridDim.x;
  const int lin = (int)blockIdx.x;
  int wg = (lin & 7) * (nwg >> 3) + (lin >> 3);
  const int z = wg / gxy; wg -= z * gxy;
  const int by = wg / gx;
  const int bx = wg - by * gx;
  const int bm = by * 256, bn = bx * 256;

  const unsigned short* A = Aall + (size_t)z * aBatch;
  const unsigned short* B = Ball + (size_t)z * bBatch;

  const int tid = threadIdx.x;           // 0..511
  const int lane = tid & 63, wid = tid >> 6;
  const int wr = wid >> 2, wc = wid & 3; // wave -> (2 x 4) output grid
  const int la31 = lane & 31, lg2 = lane >> 5;

  // ---- staging: region = 128 rows x 128 B; thread covers row tid>>3 (+64 via 2nd GLD).
  const int srow = tid >> 3;                                // 0..63
  const int sk = ((tid & 7) ^ ((srow ^ (srow >> 3)) & 7)) * 8;
  const unsigned short* aS00 = A + (size_t)(bm +   0 + srow) * K + sk;
  const unsigned short* aS01 = A + (size_t)(bm +  64 + srow) * K + sk;
  const unsigned short* aS10 = A + (size_t)(bm + 128 + srow) * K + sk;
  const unsigned short* aS11 = A + (size_t)(bm + 192 + srow) * K + sk;
  const unsigned short* bS00 = B + (size_t)(bn +   0 + srow) * K + sk;
  const unsigned short* bS01 = B + (size_t)(bn +  64 + srow) * K + sk;
  const unsigned short* bS10 = B + (size_t)(bn + 128 + srow) * K + sk;
  const unsigned short* bS11 = B + (size_t)(bn + 192 + srow) * K + sk;

// regionOff: A half0=0, A half1=16384, B half0=32768, B half1=49152
#define STG(p0, p1, regionOff, tt)                                        \
  do {                                                                    \
    char* _d = smem + (((tt) & 1) << 16) + (regionOff) + tid * 16;        \
    GLD16((p0) + (size_t)(tt) * 64, _d);                                  \
    GLD16((p1) + (size_t)(tt) * 64, _d + 8192);                           \
  } while (0)

  // ---- fragment read bases (tile-local rows; row stride 128 B)
  int aO[4], aX[4];
#pragma unroll
  for (int m = 0; m < 4; ++m) {
    const int arow = wr * 128 + m * 32 + la31;
    aO[m] = arow * 128;
    aX[m] = (arow ^ (arow >> 3)) & 7;
  }
  int bO[2], bX[2];
#pragma unroll
  for (int n = 0; n < 2; ++n) {
    const int brow = wc * 64 + n * 32 + la31;
    bO[n] = 32768 + brow * 128;
    bX[n] = (brow ^ (brow >> 3)) & 7;
  }

  f32x16 acc[4][2];
#pragma unroll
  for (int m = 0; m < 4; ++m)
#pragma unroll
    for (int n = 0; n < 2; ++n)
#pragma unroll
      for (int r = 0; r < 16; ++r) acc[m][n][r] = 0.f;

  const int NT = K >> 6;    // K-tiles of 64

  // ---- prologue: stage A(0),B(0),B(1); wait A(0),B(0) landed
  STG(aS00, aS01, 0, 0);
  STG(aS10, aS11, 16384, 0);
  STG(bS00, bS01, 32768, 0);
  STG(bS10, bS11, 49152, 0);
  STG(bS00, bS01, 32768, 1);
  STG(bS10, bS11, 49152, 1);
  VMC(4);
  BARRIER();

  short8 av[2][4], bv[2][4];

  for (int t = 0; t < NT; ++t) {
    const char* base = smem + ((t & 1) << 16);

    // ================= ph1: m0-1 x n0-1, all ks =================
#pragma unroll
    for (int m = 0; m < 2; ++m)
#pragma unroll
      for (int ks = 0; ks < 4; ++ks)
        av[m][ks] = *(const short8*)(base + aO[m] + ((((ks << 1) + lg2) ^ aX[m]) << 4));
#pragma unroll
    for (int n = 0; n < 2; ++n)
#pragma unroll
      for (int ks = 0; ks < 4; ++ks)
        bv[n][ks] = *(const short8*)(base + bO[n] + ((((ks << 1) + lg2) ^ bX[n]) << 4));
    if (t + 1 < NT) {
      STG(aS00, aS01, 0, t + 1);
      STG(aS10, aS11, 16384, t + 1);
    }
    BARRIER();
    LGKM0();
    SCHED0();
    __builtin_amdgcn_s_setprio(1);
#pragma unroll
    for (int ks = 0; ks < 4; ++ks)
#pragma unroll
      for (int m = 0; m < 2; ++m)
#pragma unroll
        for (int n = 0; n < 2; ++n)
          acc[m][n] = __builtin_amdgcn_mfma_f32_32x32x16_bf16(av[m][ks], bv[n][ks], acc[m][n], 0, 0, 0);
    __builtin_amdgcn_s_setprio(0);
    SCHED0();
    BARRIER();

    // ================= ph2: m2-3 x n0-1, all ks =================
#pragma unroll
    for (int m = 0; m < 2; ++m)
#pragma unroll
      for (int ks = 0; ks < 4; ++ks)
        av[m][ks] = *(const short8*)(base + aO[m + 2] + ((((ks << 1) + lg2) ^ aX[m + 2]) << 4));
    if (t + 2 < NT) {
      STG(bS00, bS01, 32768, t + 2);
      STG(bS10, bS11, 49152, t + 2);
    }
    BARRIER();
    LGKM0();
    SCHED0();
    __builtin_amdgcn_s_setprio(1);
#pragma unroll
    for (int ks = 0; ks < 4; ++ks)
#pragma unroll
      for (int m = 0; m < 2; ++m)
#pragma unroll
        for (int n = 0; n < 2; ++n)
          acc[m + 2][n] = __builtin_amdgcn_mfma_f32_32x32x16_bf16(av[m][ks], bv[n][ks], acc[m + 2][n], 0, 0, 0);
    __builtin_amdgcn_s_setprio(0);
    SCHED0();
    if (t + 2 < NT) {
      VMC(4);               // A(t+1),B(t+1) landed; B(t+2) stays in flight
    } else {
      VMC(0);               // tail drain (last two tiles only)
    }
    BARRIER();
  }
#undef STG

  // ---- epilogue (C/D: col = lane&31, row = (r&3) + 8*(r>>2) + 4*(lane>>5))
  float bvv[2];
  if (MODE == 0 || MODE == 1) {
    const float* bias = biasAll + (size_t)z * biasBatch;
#pragma unroll
    for (int n = 0; n < 2; ++n) bvv[n] = bias[bn + wc * 64 + n * 32 + la31];
  }
#pragma unroll
  for (int m = 0; m < 4; ++m)
#pragma unroll
    for (int n = 0; n < 2; ++n)
#pragma unroll
      for (int r = 0; r < 16; ++r) {
        const int grow = bm + wr * 128 + m * 32 + (r & 3) + 8 * (r >> 2) + 4 * lg2;
        const int gcol = bn + wc * 64 + n * 32 + la31;
        float val = acc[m][n][r];
        if (MODE == 0 || MODE == 1) val += bvv[n];
        if (MODE == 2) val *= scale;
        if (MODE == 0 || MODE == 2) {
          unsigned short* o = (unsigned short*)outAll + (size_t)z * outBatch;
          o[(size_t)grow * ldOut + gcol] = f2bf(val);
        } else if (MODE == 1) {
          unsigned short* o = (unsigned short*)outAll + (size_t)z * outBatch;
          o[(size_t)gcol * ldOut + grow] = f2bf(val);
        } else {
          float* o = (float*)outAll + (size_t)z * outBatch;
          o[(size_t)grow * ldOut + gcol] = val;
        }
      }
}

// ---------------- row softmax, in place on bf16 [nrows][SEQ] ----------------
__global__ __launch_bounds__(256) void softmax_kernel(unsigned short* __restrict__ Sb) {
  const size_t row = blockIdx.x;
  unsigned short* p = Sb + row * (size_t)SEQ;
  const int tid = threadIdx.x;
  const int lane = tid & 63, wid = tid >> 6;
  float v[16];
  const short8 u0 = *(const short8*)&p[tid * 16];
  const short8 u1 = *(const short8*)&p[tid * 16 + 8];
#pragma unroll
  for (int j = 0; j < 8; ++j) v[j] = bf2f((unsigned short)u0[j]);
#pragma unroll
  for (int j = 0; j < 8; ++j) v[8 + j] = bf2f((unsigned short)u1[j]);
  float mx = v[0];
#pragma unroll
  for (int j = 1; j < 16; ++j) mx = fmaxf(mx, v[j]);
#pragma unroll
  for (int off = 32; off; off >>= 1) mx = fmaxf(mx, __shfl_xor(mx, off));
  __shared__ float red[8];
  if (lane == 0) red[wid] = mx;
  __syncthreads();
  mx = fmaxf(fmaxf(red[0], red[1]), fmaxf(red[2], red[3]));
  float s = 0.f;
#pragma unroll
  for (int j = 0; j < 16; ++j) { v[j] = __expf(v[j] - mx); s += v[j]; }
#pragma unroll
  for (int off = 32; off; off >>= 1) s += __shfl_xor(s, off);
  if (lane == 0) red[4 + wid] = s;
  __syncthreads();
  s = (red[4] + red[5]) + (red[6] + red[7]);
  const float inv = 1.0f / s;
  short8 o0, o1;
#pragma unroll
  for (int j = 0; j < 8; ++j) o0[j] = (short)f2bf(v[j] * inv);
#pragma unroll
  for (int j = 0; j < 8; ++j) o1[j] = (short)f2bf(v[8 + j] * inv);
  *(short8*)&p[tid * 16] = o0;
  *(short8*)&p[tid * 16 + 8] = o1;
}

extern "C" void kernel_launch(void* const* d_in, const int* in_sizes, int n_in,
                              void* d_out, int out_size, void* d_ws, size_t ws_size,
                              hipStream_t stream) {
  const float* h  = (const float*)d_in[0];
  const float* Wq = (const float*)d_in[1];
  const float* bq = (const float*)d_in[2];
  const float* Wk = (const float*)d_in[3];
  const float* bk = (const float*)d_in[4];
  const float* Wv = (const float*)d_in[5];
  const float* bv = (const float*)d_in[6];
  float* out = (float*)d_out;
  char* ws = (char*)d_ws;

  // allow 128KB dynamic LDS for the GEMM kernels (idempotent, not a stream op)
  (void)hipFuncSetAttribute((const void*)&gemm256_kernel<0>,
                            hipFuncAttributeMaxDynamicSharedMemorySize, 131072);
  (void)hipFuncSetAttribute((const void*)&gemm256_kernel<1>,
                            hipFuncAttributeMaxDynamicSharedMemorySize, 131072);
  (void)hipFuncSetAttribute((const void*)&gemm256_kernel<2>,
                            hipFuncAttributeMaxDynamicSharedMemorySize, 131072);
  (void)hipFuncSetAttribute((const void*)&gemm256_kernel<3>,
                            hipFuncAttributeMaxDynamicSharedMemorySize, 131072);

  // ws layout (224 MB):
  //  [0,32MB)    h_bf16 [S][HID]          -- dead after projections
  //  [32,128MB)  Wt bf16 [12][E][HID]     -- dead after projections
  //  [0,128MB)   Sb bf16 [H][S][S]        -- scores/probs (reuses the two above)
  //  [128,160)   Qb bf16 [H][S][E]
  //  [160,192)   Kb bf16 [H][S][E]
  //  [192,224)   Vt bf16 [H][E][S]
  unsigned short* hB = (unsigned short*)ws;
  unsigned short* wt = (unsigned short*)(ws + (32ull << 20));
  unsigned short* Sb = (unsigned short*)ws;
  unsigned short* Qb = (unsigned short*)(ws + (128ull << 20));
  unsigned short* Kb = (unsigned short*)(ws + (160ull << 20));
  unsigned short* Vt = (unsigned short*)(ws + (192ull << 20));

  const long long WED = (long long)EDIM * HID;   // per-(mat,head) Wt elems
  const long long QKB = (long long)SEQ * EDIM;   // per-head Q/K elems
  const long long SSB = (long long)SEQ * SEQ;    // per-head score elems

  hconv_kernel<<<dim3((SEQ * (size_t)HID) / (256 * 8)), 256, 0, stream>>>(h, hB);
  wconv_kernel<<<dim3((HID / 64) * (EDIM / 64), 12), 256, 0, stream>>>(Wq, Wk, Wv, wt);

  // Projections: M=S=4096, N=E=1024, K=HID  -> grid (4 x 16 x 4) = 256 blocks, 1-D
  gemm256_kernel<0><<<dim3(4 * 16 * 4), 512, 131072, stream>>>(
      hB, wt + 0 * WED, 0, WED, HID, bq, EDIM, Qb, QKB, EDIM, 1.f, 4, 64);
  gemm256_kernel<0><<<dim3(4 * 16 * 4), 512, 131072, stream>>>(
      hB, wt + 4 * WED, 0, WED, HID, bk, EDIM, Kb, QKB, EDIM, 1.f, 4, 64);
  gemm256_kernel<1><<<dim3(4 * 16 * 4), 512, 131072, stream>>>(
      hB, wt + 8 * WED, 0, WED, HID, bv, EDIM, Vt, QKB, SEQ, 1.f, 4, 64);

  // Scores: S = Q K^T / 32   (M=N=S, K=E) -> grid (16 x 16 x 4) = 1024 blocks
  gemm256_kernel<2><<<dim3(16 * 16 * 4), 512, 131072, stream>>>(
      Qb, Kb, QKB, QKB, EDIM, nullptr, 0, Sb, SSB, SEQ, 0.03125f, 16, 256);

  // Softmax over rows, in place
  softmax_kernel<<<dim3(NHEAD * SEQ), 256, 0, stream>>>(Sb);

  // Out: O = P V  (M=S, N=E, K=S), written to out[s][head*E + e] as f32
  gemm256_kernel<3><<<dim3(4 * 16 * 4), 512, 131072, stream>>>(
      Sb, Vt, SSB, QKB, SEQ, nullptr, 0, out, (long long)EDIM, NHEAD * EDIM, 1.f, 4, 64);
}